// Round 2
// baseline (315.662 us; speedup 1.0000x reference)
//
#include <hip/hip_runtime.h>

// B=8, N=2048, D_IN=D_OUT=512. out fp32 [8,2048,512].
// ws layout (bytes): xb@0 (16M), Qb@16M, Kb@32M, Vt@48M, Wt@64M(+1.5M).

typedef __bf16 bf16x8 __attribute__((ext_vector_type(8)));
typedef float f32x4 __attribute__((ext_vector_type(4)));

#define AS1G __attribute__((address_space(1)))
#define AS3L __attribute__((address_space(3)))

__device__ __forceinline__ void gload16(const void* g, void* l) {
  __builtin_amdgcn_global_load_lds((const AS1G void*)g, (AS3L void*)l, 16, 0, 0);
}

// ---------------- x fp32 -> bf16 ----------------
__global__ __launch_bounds__(256) void k_xconv(const float* __restrict__ x, __bf16* __restrict__ xb) {
  size_t i = ((size_t)blockIdx.x * 256 + threadIdx.x) * 8;
  const float4* p = (const float4*)(x + i);
  float4 a = p[0], b = p[1];
  bf16x8 v;
  v[0] = (__bf16)a.x; v[1] = (__bf16)a.y; v[2] = (__bf16)a.z; v[3] = (__bf16)a.w;
  v[4] = (__bf16)b.x; v[5] = (__bf16)b.y; v[6] = (__bf16)b.z; v[7] = (__bf16)b.w;
  *(bf16x8*)(xb + i) = v;
}

// ---------------- W [d][e] fp32 -> Wt [z][e][d] bf16 ----------------
__global__ __launch_bounds__(256) void k_wt(const float* __restrict__ Wq, const float* __restrict__ Wk,
                                            const float* __restrict__ Wv, __bf16* __restrict__ Wt) {
  __shared__ float t[32][33];
  int z = blockIdx.z;
  const float* W = (z == 0) ? Wq : (z == 1 ? Wk : Wv);
  int r0 = blockIdx.y * 32, c0 = blockIdx.x * 32;
  int tr = threadIdx.x >> 5, tc = threadIdx.x & 31;
#pragma unroll
  for (int p = 0; p < 4; p++)
    t[tr + p * 8][tc] = W[(size_t)(r0 + tr + p * 8) * 512 + c0 + tc];
  __syncthreads();
#pragma unroll
  for (int p = 0; p < 4; p++)
    Wt[(size_t)z * 262144 + (size_t)(c0 + tr + p * 8) * 512 + r0 + tc] = (__bf16)t[tc][tr + p * 8];
}

// ---------------- fused QKV GEMM: C = xb * Wz^T + bias ----------------
// 128x128 tile, BK=64, 4 waves (2x2 of 64x64), 16x16x32 bf16 MFMA.
// z==0 -> Qb (pre-scaled for exp2 softmax), z==1 -> Kb, z==2 -> Vt (TRANSPOSED store).
__global__ __launch_bounds__(256) void k_gemm(const __bf16* __restrict__ xb, const __bf16* __restrict__ Wt,
                                              const float* __restrict__ bq, const float* __restrict__ bk,
                                              const float* __restrict__ bv,
                                              __bf16* __restrict__ Qb, __bf16* __restrict__ Kb,
                                              __bf16* __restrict__ Vt) {
  __shared__ __bf16 sA[128 * 64];
  __shared__ __bf16 sB[128 * 64];
  int z = blockIdx.y;
  int bx = blockIdx.x;
  int m0 = (bx >> 2) * 128, e0 = (bx & 3) * 128;
  int tid = threadIdx.x, w = tid >> 6, l = tid & 63;
  int lr = l & 15, lg = l >> 4;
  int wm = (w & 1) * 64, wn = (w >> 1) * 64;
  const float* bias = (z == 0) ? bq : (z == 1 ? bk : bv);
  const __bf16* Wz = Wt + (size_t)z * 262144;

  float bval[4];
#pragma unroll
  for (int fn = 0; fn < 4; fn++) bval[fn] = bias[e0 + wn + fn * 16 + lr];

  f32x4 zero4 = {0.f, 0.f, 0.f, 0.f};
  f32x4 acc[4][4];
#pragma unroll
  for (int fm = 0; fm < 4; fm++)
#pragma unroll
    for (int fn = 0; fn < 4; fn++) acc[fm][fn] = zero4;

#pragma unroll 1
  for (int kt = 0; kt < 8; kt++) {
#pragma unroll
    for (int ii = 0; ii < 4; ii++) {
      int rt = (w * 4 + ii) * 8 + (l >> 3);
      int sw = ((l & 7) ^ (l >> 3)) << 3;
      gload16(xb + (size_t)(m0 + rt) * 512 + kt * 64 + sw, sA + (w * 4 + ii) * 512);
      gload16(Wz + (size_t)(e0 + rt) * 512 + kt * 64 + sw, sB + (w * 4 + ii) * 512);
    }
    __syncthreads();
#pragma unroll
    for (int kc = 0; kc < 2; kc++) {
      bf16x8 af[4], bfr[4];
#pragma unroll
      for (int f = 0; f < 4; f++) {
        int ra = wm + f * 16 + lr;
        af[f] = *(const bf16x8*)(sA + ra * 64 + (((kc * 4 + lg) ^ (ra & 7)) << 3));
        int rb = wn + f * 16 + lr;
        bfr[f] = *(const bf16x8*)(sB + rb * 64 + (((kc * 4 + lg) ^ (rb & 7)) << 3));
      }
#pragma unroll
      for (int fm = 0; fm < 4; fm++)
#pragma unroll
        for (int fn = 0; fn < 4; fn++)
          acc[fm][fn] = __builtin_amdgcn_mfma_f32_16x16x32_bf16(af[fm], bfr[fn], acc[fm][fn], 0, 0, 0);
    }
    __syncthreads();
  }

  if (z == 2) {
    // V transposed: Vt[b][e][n], b = row>>11, n = row&2047. 4 consecutive n per lane -> 8B store.
    int bb = m0 >> 11;
#pragma unroll
    for (int fm = 0; fm < 4; fm++) {
      int nl = (m0 & 2047) + wm + fm * 16 + lg * 4;
#pragma unroll
      for (int fn = 0; fn < 4; fn++) {
        alignas(8) __bf16 tmp[4];
#pragma unroll
        for (int r = 0; r < 4; r++) tmp[r] = (__bf16)(acc[fm][fn][r] + bval[fn]);
        *(float2*)(Vt + (size_t)bb * 1048576 + (size_t)(e0 + wn + fn * 16 + lr) * 2048 + nl) =
            *(float2*)tmp;
      }
    }
  } else {
    __bf16* dst = (z == 0) ? Qb : Kb;
    const float qmul = (z == 0) ? (1.4426950408889634f * 0.044194173824159216f) : 1.0f;
#pragma unroll
    for (int fm = 0; fm < 4; fm++)
#pragma unroll
      for (int fn = 0; fn < 4; fn++)
#pragma unroll
        for (int r = 0; r < 4; r++) {
          float v = (acc[fm][fn][r] + bval[fn]) * qmul;
          dst[(size_t)(m0 + wm + fm * 16 + lg * 4 + r) * 512 + e0 + wn + fn * 16 + lr] = (__bf16)v;
        }
  }
}

// ---------------- flash attention, intra-block KV split ----------------
// grid 256 (b = blk&7, qtile = blk>>3), 512 threads = 2 groups x 4 waves.
// Group g handles KV tiles kv0 = (2*it+g)*32, it in [0,32). 64 q-rows/block, 16 per wave.
// LDS per group: sK[32][512] (XOR-8 chunk swz) + sV[256][64] (paired d-rows, XOR swz).
// Staging overlap: V(it) staged during QK(it); K(it+1) staged during softmax+PV(it).
// End: group partials merged via LDS (oX aliases sK/sV region).
__global__ __launch_bounds__(512, 2) void k_fa(const __bf16* __restrict__ Qb, const __bf16* __restrict__ Kb,
                                               const __bf16* __restrict__ Vt, float* __restrict__ out) {
  extern __shared__ char smem[];
  int tid = threadIdx.x;
  int w = tid >> 6, l = tid & 63;
  int g = w >> 2, wg = w & 3;
  int lr = l & 15, lg = l >> 4;
  __bf16* sK = (__bf16*)(smem + g * 65536);          // [32][512]
  __bf16* sV = (__bf16*)(smem + g * 65536 + 32768);  // [256][64] paired rows
  __bf16* sP = (__bf16*)(smem + 131072) + w * 640;   // per-wave [16][40]
  float* mX = (float*)(smem + 141312);
  float* lX = (float*)(smem + 141312 + 256);

  int b = blockIdx.x & 7;
  int q0 = (blockIdx.x >> 3) * 64;

  const __bf16* Kbase = Kb + (size_t)b * 2048 * 512;
  const __bf16* Vbase = Vt + (size_t)b * 512 * 2048;

  // Q A-fragments in registers (already scaled by log2e/sqrt(512)).
  bf16x8 qf[16];
  const __bf16* qrow = Qb + (size_t)(b * 2048 + q0 + wg * 16 + lr) * 512;
#pragma unroll
  for (int dk = 0; dk < 16; dk++) qf[dk] = *(const bf16x8*)(qrow + dk * 32 + lg * 8);

  f32x4 zero4 = {0.f, 0.f, 0.f, 0.f};
  f32x4 o[32];
#pragma unroll
  for (int dj = 0; dj < 32; dj++) o[dj] = zero4;
  float m_run[4] = {-1e30f, -1e30f, -1e30f, -1e30f};
  float l_run[4] = {0.f, 0.f, 0.f, 0.f};

  // prologue: stage K(0) for own group
  {
    int kv0 = g * 32;
#pragma unroll
    for (int i = 0; i < 8; i++) {
      int row = wg * 8 + i;
      gload16(Kbase + (size_t)(kv0 + row) * 512 + ((l ^ i) << 3), sK + row * 512);
    }
  }

#pragma unroll 1
  for (int it = 0; it < 32; it++) {
    int kv0 = (it * 2 + g) * 32;
    __syncthreads();  // B1: K(it) landed; all PV(it-1) LDS reads done

    // stage V(it) — overlaps QK
#pragma unroll
    for (int i = 0; i < 8; i++) {
      int R0 = wg * 64 + i * 8;
      int r = R0 + (l >> 3);
      int cl = (l & 7) ^ (r & 7);
      gload16(Vbase + (size_t)(2 * r + (cl >> 2)) * 2048 + kv0 + ((cl & 3) << 3), sV + R0 * 64);
    }

    // S = Q K^T (exp2 domain)
    f32x4 s[2] = {zero4, zero4};
#pragma unroll
    for (int dk = 0; dk < 16; dk++) {
#pragma unroll
      for (int j = 0; j < 2; j++) {
        int row = j * 16 + lr;
        bf16x8 kf = *(const bf16x8*)(sK + row * 512 + (((dk * 4 + lg) ^ (row & 7)) << 3));
        s[j] = __builtin_amdgcn_mfma_f32_16x16x32_bf16(qf[dk], kf, s[j], 0, 0, 0);
      }
    }
    __syncthreads();  // B2: V(it) landed (vmcnt drain); all sK reads done

    // stage K(it+1) — overlaps softmax+PV
    if (it < 31) {
      int kv0n = ((it + 1) * 2 + g) * 32;
#pragma unroll
      for (int i = 0; i < 8; i++) {
        int row = wg * 8 + i;
        gload16(Kbase + (size_t)(kv0n + row) * 512 + ((l ^ i) << 3), sK + row * 512);
      }
    }

    // online softmax with defer-rescale (THR=10 in log2 domain)
    float mtv[4];
#pragma unroll
    for (int r = 0; r < 4; r++) {
      float mt = fmaxf(s[0][r], s[1][r]);
#pragma unroll
      for (int msk = 1; msk <= 8; msk <<= 1) mt = fmaxf(mt, __shfl_xor(mt, msk));
      mtv[r] = mt;
    }
    float g4 = fmaxf(fmaxf(mtv[0] - m_run[0], mtv[1] - m_run[1]),
                     fmaxf(mtv[2] - m_run[2], mtv[3] - m_run[3]));
    if (__any(g4 > 10.0f)) {
#pragma unroll
      for (int r = 0; r < 4; r++) {
        float mnew = fmaxf(m_run[r], mtv[r]);
        float al = exp2f(m_run[r] - mnew);
        l_run[r] *= al;
        m_run[r] = mnew;
#pragma unroll
        for (int dj = 0; dj < 32; dj++) o[dj][r] *= al;
      }
    }
#pragma unroll
    for (int r = 0; r < 4; r++) {
      float p0 = exp2f(s[0][r] - m_run[r]);
      float p1 = exp2f(s[1][r] - m_run[r]);
      l_run[r] += p0 + p1;  // per-lane partial over lr columns
      sP[(lg * 4 + r) * 40 + lr] = (__bf16)p0;
      sP[(lg * 4 + r) * 40 + 16 + lr] = (__bf16)p1;
    }
    bf16x8 pa = *(const bf16x8*)(sP + lr * 40 + lg * 8);

    // O += P * V  (V from paired-row swizzled sV)
#pragma unroll
    for (int dj = 0; dj < 32; dj++) {
      int d = dj * 16 + lr;
      int rr = d >> 1;
      int cp = (((d & 1) << 2) | lg) ^ (rr & 7);
      bf16x8 vf = *(const bf16x8*)(sV + rr * 64 + (cp << 3));
      o[dj] = __builtin_amdgcn_mfma_f32_16x16x32_bf16(pa, vf, o[dj], 0, 0, 0);
    }
  }

  // finish per-lane l partials -> per-row sums
#pragma unroll
  for (int r = 0; r < 4; r++) {
#pragma unroll
    for (int msk = 1; msk <= 8; msk <<= 1) l_run[r] += __shfl_xor(l_run[r], msk);
  }

  __syncthreads();  // loop fully done; sK/sV region reusable as oX
  float* oX = (float*)smem;  // [64][512] f32
  if (g == 1) {
#pragma unroll
    for (int r = 0; r < 4; r++) {
      int row = wg * 16 + lg * 4 + r;
#pragma unroll
      for (int dj = 0; dj < 32; dj++) oX[row * 512 + dj * 16 + lr] = o[dj][r];
      if (lr == 0) { mX[row] = m_run[r]; lX[row] = l_run[r]; }
    }
  }
  __syncthreads();
  if (g == 0) {
    float s0[4], s1[4];
    int rowb = wg * 16 + lg * 4;
#pragma unroll
    for (int r = 0; r < 4; r++) {
      float mB = mX[rowb + r], lB = lX[rowb + r];
      float m = fmaxf(m_run[r], mB);
      float a0 = exp2f(m_run[r] - m), a1 = exp2f(mB - m);
      float inv = 1.0f / (l_run[r] * a0 + lB * a1);
      s0[r] = a0 * inv;
      s1[r] = a1 * inv;
    }
    float* orow = out + (size_t)(b * 2048 + q0 + rowb) * 512;
#pragma unroll
    for (int dj = 0; dj < 32; dj++)
#pragma unroll
      for (int r = 0; r < 4; r++)
        orow[(size_t)r * 512 + dj * 16 + lr] =
            o[dj][r] * s0[r] + oX[(rowb + r) * 512 + dj * 16 + lr] * s1[r];
  }
}

extern "C" void kernel_launch(void* const* d_in, const int* in_sizes, int n_in,
                              void* d_out, int out_size, void* d_ws, size_t ws_size,
                              hipStream_t stream) {
  (void)in_sizes; (void)n_in; (void)out_size; (void)ws_size;
  const float* x = (const float*)d_in[0];
  const float* Wq = (const float*)d_in[1];
  const float* bq = (const float*)d_in[2];
  const float* Wk = (const float*)d_in[3];
  const float* bk = (const float*)d_in[4];
  const float* Wv = (const float*)d_in[5];
  const float* bv = (const float*)d_in[6];
  float* out = (float*)d_out;
  char* ws = (char*)d_ws;
  __bf16* xb = (__bf16*)(ws);
  __bf16* Qb = (__bf16*)(ws + 16777216);
  __bf16* Kb = (__bf16*)(ws + 33554432);
  __bf16* Vt = (__bf16*)(ws + 50331648);
  __bf16* Wt = (__bf16*)(ws + 67108864);

  hipFuncSetAttribute((const void*)k_fa, hipFuncAttributeMaxDynamicSharedMemorySize, 141824);

  k_xconv<<<4096, 256, 0, stream>>>(x, xb);
  k_wt<<<dim3(16, 16, 3), 256, 0, stream>>>(Wq, Wk, Wv, Wt);
  k_gemm<<<dim3(512, 3), 256, 0, stream>>>(xb, Wt, bq, bk, bv, Qb, Kb, Vt);
  k_fa<<<256, 512, 141824, stream>>>(Qb, Kb, Vt, out);
}

// Round 3
// 315.042 us; speedup vs baseline: 1.0020x; 1.0020x over previous
//
#include <hip/hip_runtime.h>

// B=8, N=2048, D_IN=D_OUT=512. out fp32 [8,2048,512].
// ws layout (bytes): xb@0 (16M), Qb@16M, Kb@32M, Vt@48M, Wt@64M(+1.5M).

typedef __bf16 bf16x8 __attribute__((ext_vector_type(8)));
typedef float f32x4 __attribute__((ext_vector_type(4)));

#define AS1G __attribute__((address_space(1)))
#define AS3L __attribute__((address_space(3)))

__device__ __forceinline__ void gload16(const void* g, void* l) {
  __builtin_amdgcn_global_load_lds((const AS1G void*)g, (AS3L void*)l, 16, 0, 0);
}

// ---------------- x fp32 -> bf16 ----------------
__global__ __launch_bounds__(256) void k_xconv(const float* __restrict__ x, __bf16* __restrict__ xb) {
  size_t i = ((size_t)blockIdx.x * 256 + threadIdx.x) * 8;
  const float4* p = (const float4*)(x + i);
  float4 a = p[0], b = p[1];
  bf16x8 v;
  v[0] = (__bf16)a.x; v[1] = (__bf16)a.y; v[2] = (__bf16)a.z; v[3] = (__bf16)a.w;
  v[4] = (__bf16)b.x; v[5] = (__bf16)b.y; v[6] = (__bf16)b.z; v[7] = (__bf16)b.w;
  *(bf16x8*)(xb + i) = v;
}

// ---------------- W [d][e] fp32 -> Wt [z][e][d] bf16 ----------------
__global__ __launch_bounds__(256) void k_wt(const float* __restrict__ Wq, const float* __restrict__ Wk,
                                            const float* __restrict__ Wv, __bf16* __restrict__ Wt) {
  __shared__ float t[32][33];
  int z = blockIdx.z;
  const float* W = (z == 0) ? Wq : (z == 1 ? Wk : Wv);
  int r0 = blockIdx.y * 32, c0 = blockIdx.x * 32;
  int tr = threadIdx.x >> 5, tc = threadIdx.x & 31;
#pragma unroll
  for (int p = 0; p < 4; p++)
    t[tr + p * 8][tc] = W[(size_t)(r0 + tr + p * 8) * 512 + c0 + tc];
  __syncthreads();
#pragma unroll
  for (int p = 0; p < 4; p++)
    Wt[(size_t)z * 262144 + (size_t)(c0 + tr + p * 8) * 512 + r0 + tc] = (__bf16)t[tc][tr + p * 8];
}

// ---------------- fused QKV GEMM: C = xb * Wz^T + bias ----------------
// 128x128 tile, BK=64, 4 waves (2x2 of 64x64), 16x16x32 bf16 MFMA.
// z==0 -> Qb (pre-scaled for exp2 softmax), z==1 -> Kb, z==2 -> Vt (TRANSPOSED store).
__global__ __launch_bounds__(256) void k_gemm(const __bf16* __restrict__ xb, const __bf16* __restrict__ Wt,
                                              const float* __restrict__ bq, const float* __restrict__ bk,
                                              const float* __restrict__ bv,
                                              __bf16* __restrict__ Qb, __bf16* __restrict__ Kb,
                                              __bf16* __restrict__ Vt) {
  __shared__ __bf16 sA[128 * 64];
  __shared__ __bf16 sB[128 * 64];
  int z = blockIdx.y;
  int bx = blockIdx.x;
  int m0 = (bx >> 2) * 128, e0 = (bx & 3) * 128;
  int tid = threadIdx.x, w = tid >> 6, l = tid & 63;
  int lr = l & 15, lg = l >> 4;
  int wm = (w & 1) * 64, wn = (w >> 1) * 64;
  const float* bias = (z == 0) ? bq : (z == 1 ? bk : bv);
  const __bf16* Wz = Wt + (size_t)z * 262144;

  float bval[4];
#pragma unroll
  for (int fn = 0; fn < 4; fn++) bval[fn] = bias[e0 + wn + fn * 16 + lr];

  f32x4 zero4 = {0.f, 0.f, 0.f, 0.f};
  f32x4 acc[4][4];
#pragma unroll
  for (int fm = 0; fm < 4; fm++)
#pragma unroll
    for (int fn = 0; fn < 4; fn++) acc[fm][fn] = zero4;

#pragma unroll 1
  for (int kt = 0; kt < 8; kt++) {
#pragma unroll
    for (int ii = 0; ii < 4; ii++) {
      int rt = (w * 4 + ii) * 8 + (l >> 3);
      int sw = ((l & 7) ^ (l >> 3)) << 3;
      gload16(xb + (size_t)(m0 + rt) * 512 + kt * 64 + sw, sA + (w * 4 + ii) * 512);
      gload16(Wz + (size_t)(e0 + rt) * 512 + kt * 64 + sw, sB + (w * 4 + ii) * 512);
    }
    __syncthreads();
#pragma unroll
    for (int kc = 0; kc < 2; kc++) {
      bf16x8 af[4], bfr[4];
#pragma unroll
      for (int f = 0; f < 4; f++) {
        int ra = wm + f * 16 + lr;
        af[f] = *(const bf16x8*)(sA + ra * 64 + (((kc * 4 + lg) ^ (ra & 7)) << 3));
        int rb = wn + f * 16 + lr;
        bfr[f] = *(const bf16x8*)(sB + rb * 64 + (((kc * 4 + lg) ^ (rb & 7)) << 3));
      }
#pragma unroll
      for (int fm = 0; fm < 4; fm++)
#pragma unroll
        for (int fn = 0; fn < 4; fn++)
          acc[fm][fn] = __builtin_amdgcn_mfma_f32_16x16x32_bf16(af[fm], bfr[fn], acc[fm][fn], 0, 0, 0);
    }
    __syncthreads();
  }

  if (z == 2) {
    // V transposed: Vt[b][e][n], b = row>>11, n = row&2047. 4 consecutive n per lane -> 8B store.
    int bb = m0 >> 11;
#pragma unroll
    for (int fm = 0; fm < 4; fm++) {
      int nl = (m0 & 2047) + wm + fm * 16 + lg * 4;
#pragma unroll
      for (int fn = 0; fn < 4; fn++) {
        alignas(8) __bf16 tmp[4];
#pragma unroll
        for (int r = 0; r < 4; r++) tmp[r] = (__bf16)(acc[fm][fn][r] + bval[fn]);
        *(float2*)(Vt + (size_t)bb * 1048576 + (size_t)(e0 + wn + fn * 16 + lr) * 2048 + nl) =
            *(float2*)tmp;
      }
    }
  } else {
    __bf16* dst = (z == 0) ? Qb : Kb;
    const float qmul = (z == 0) ? (1.4426950408889634f * 0.044194173824159216f) : 1.0f;
#pragma unroll
    for (int fm = 0; fm < 4; fm++)
#pragma unroll
      for (int fn = 0; fn < 4; fn++)
#pragma unroll
        for (int r = 0; r < 4; r++) {
          float v = (acc[fm][fn][r] + bval[fn]) * qmul;
          dst[(size_t)(m0 + wm + fm * 16 + lg * 4 + r) * 512 + e0 + wn + fn * 16 + lr] = (__bf16)v;
        }
  }
}

// ---------------- flash attention, intra-block KV split ----------------
// grid 256 (b = blk&7, qtile = blk>>3), 512 threads = 2 groups x 4 waves.
// Group g handles KV tiles kv0 = (2*it+g)*32, it in [0,32). 64 q-rows/block, 16 per wave.
// LDS per group: sK[32][512] (XOR-8 chunk swz) + sV[256][64] (paired d-rows, XOR swz).
// Staging overlap: V(it) staged during QK(it); K(it+1) staged during softmax+PV(it).
// End: group partials merged via LDS (oX aliases sK/sV region).
// NOTE: launch_bounds(512,1) — (512,2) capped VGPR at 128 and spilled o[32]+qf[16]
// (~230 live regs) to scratch: WRITE_SIZE +21MB, dur 271us. ~240 VGPR still fits
// 2 waves/SIMD (<=256 step); LDS already limits to 1 block/CU.
__global__ __launch_bounds__(512, 1) void k_fa(const __bf16* __restrict__ Qb, const __bf16* __restrict__ Kb,
                                               const __bf16* __restrict__ Vt, float* __restrict__ out) {
  extern __shared__ char smem[];
  int tid = threadIdx.x;
  int w = tid >> 6, l = tid & 63;
  int g = w >> 2, wg = w & 3;
  int lr = l & 15, lg = l >> 4;
  __bf16* sK = (__bf16*)(smem + g * 65536);          // [32][512]
  __bf16* sV = (__bf16*)(smem + g * 65536 + 32768);  // [256][64] paired rows
  __bf16* sP = (__bf16*)(smem + 131072) + w * 640;   // per-wave [16][40]
  float* mX = (float*)(smem + 141312);
  float* lX = (float*)(smem + 141312 + 256);

  int b = blockIdx.x & 7;
  int q0 = (blockIdx.x >> 3) * 64;

  const __bf16* Kbase = Kb + (size_t)b * 2048 * 512;
  const __bf16* Vbase = Vt + (size_t)b * 512 * 2048;

  // Q A-fragments in registers (already scaled by log2e/sqrt(512)).
  bf16x8 qf[16];
  const __bf16* qrow = Qb + (size_t)(b * 2048 + q0 + wg * 16 + lr) * 512;
#pragma unroll
  for (int dk = 0; dk < 16; dk++) qf[dk] = *(const bf16x8*)(qrow + dk * 32 + lg * 8);

  f32x4 zero4 = {0.f, 0.f, 0.f, 0.f};
  f32x4 o[32];
#pragma unroll
  for (int dj = 0; dj < 32; dj++) o[dj] = zero4;
  float m_run[4] = {-1e30f, -1e30f, -1e30f, -1e30f};
  float l_run[4] = {0.f, 0.f, 0.f, 0.f};

  // prologue: stage K(0) for own group
  {
    int kv0 = g * 32;
#pragma unroll
    for (int i = 0; i < 8; i++) {
      int row = wg * 8 + i;
      gload16(Kbase + (size_t)(kv0 + row) * 512 + ((l ^ i) << 3), sK + row * 512);
    }
  }

#pragma unroll 1
  for (int it = 0; it < 32; it++) {
    int kv0 = (it * 2 + g) * 32;
    __syncthreads();  // B1: K(it) landed; all PV(it-1) LDS reads done

    // stage V(it) — overlaps QK
#pragma unroll
    for (int i = 0; i < 8; i++) {
      int R0 = wg * 64 + i * 8;
      int r = R0 + (l >> 3);
      int cl = (l & 7) ^ (r & 7);
      gload16(Vbase + (size_t)(2 * r + (cl >> 2)) * 2048 + kv0 + ((cl & 3) << 3), sV + R0 * 64);
    }

    // S = Q K^T (exp2 domain)
    f32x4 s[2] = {zero4, zero4};
#pragma unroll
    for (int dk = 0; dk < 16; dk++) {
#pragma unroll
      for (int j = 0; j < 2; j++) {
        int row = j * 16 + lr;
        bf16x8 kf = *(const bf16x8*)(sK + row * 512 + (((dk * 4 + lg) ^ (row & 7)) << 3));
        s[j] = __builtin_amdgcn_mfma_f32_16x16x32_bf16(qf[dk], kf, s[j], 0, 0, 0);
      }
    }
    __syncthreads();  // B2: V(it) landed (vmcnt drain); all sK reads done

    // stage K(it+1) — overlaps softmax+PV
    if (it < 31) {
      int kv0n = ((it + 1) * 2 + g) * 32;
#pragma unroll
      for (int i = 0; i < 8; i++) {
        int row = wg * 8 + i;
        gload16(Kbase + (size_t)(kv0n + row) * 512 + ((l ^ i) << 3), sK + row * 512);
      }
    }

    // online softmax with defer-rescale (THR=10 in log2 domain)
    float mtv[4];
#pragma unroll
    for (int r = 0; r < 4; r++) {
      float mt = fmaxf(s[0][r], s[1][r]);
#pragma unroll
      for (int msk = 1; msk <= 8; msk <<= 1) mt = fmaxf(mt, __shfl_xor(mt, msk));
      mtv[r] = mt;
    }
    float g4 = fmaxf(fmaxf(mtv[0] - m_run[0], mtv[1] - m_run[1]),
                     fmaxf(mtv[2] - m_run[2], mtv[3] - m_run[3]));
    if (__any(g4 > 10.0f)) {
#pragma unroll
      for (int r = 0; r < 4; r++) {
        float mnew = fmaxf(m_run[r], mtv[r]);
        float al = exp2f(m_run[r] - mnew);
        l_run[r] *= al;
        m_run[r] = mnew;
#pragma unroll
        for (int dj = 0; dj < 32; dj++) o[dj][r] *= al;
      }
    }
#pragma unroll
    for (int r = 0; r < 4; r++) {
      float p0 = exp2f(s[0][r] - m_run[r]);
      float p1 = exp2f(s[1][r] - m_run[r]);
      l_run[r] += p0 + p1;  // per-lane partial over lr columns
      sP[(lg * 4 + r) * 40 + lr] = (__bf16)p0;
      sP[(lg * 4 + r) * 40 + 16 + lr] = (__bf16)p1;
    }
    bf16x8 pa = *(const bf16x8*)(sP + lr * 40 + lg * 8);

    // O += P * V  (V from paired-row swizzled sV)
#pragma unroll
    for (int dj = 0; dj < 32; dj++) {
      int d = dj * 16 + lr;
      int rr = d >> 1;
      int cp = (((d & 1) << 2) | lg) ^ (rr & 7);
      bf16x8 vf = *(const bf16x8*)(sV + rr * 64 + (cp << 3));
      o[dj] = __builtin_amdgcn_mfma_f32_16x16x32_bf16(pa, vf, o[dj], 0, 0, 0);
    }
  }

  // finish per-lane l partials -> per-row sums
#pragma unroll
  for (int r = 0; r < 4; r++) {
#pragma unroll
    for (int msk = 1; msk <= 8; msk <<= 1) l_run[r] += __shfl_xor(l_run[r], msk);
  }

  __syncthreads();  // loop fully done; sK/sV region reusable as oX
  float* oX = (float*)smem;  // [64][512] f32
  if (g == 1) {
#pragma unroll
    for (int r = 0; r < 4; r++) {
      int row = wg * 16 + lg * 4 + r;
#pragma unroll
      for (int dj = 0; dj < 32; dj++) oX[row * 512 + dj * 16 + lr] = o[dj][r];
      if (lr == 0) { mX[row] = m_run[r]; lX[row] = l_run[r]; }
    }
  }
  __syncthreads();
  if (g == 0) {
    float s0[4], s1[4];
    int rowb = wg * 16 + lg * 4;
#pragma unroll
    for (int r = 0; r < 4; r++) {
      float mB = mX[rowb + r], lB = lX[rowb + r];
      float m = fmaxf(m_run[r], mB);
      float a0 = exp2f(m_run[r] - m), a1 = exp2f(mB - m);
      float inv = 1.0f / (l_run[r] * a0 + lB * a1);
      s0[r] = a0 * inv;
      s1[r] = a1 * inv;
    }
    float* orow = out + (size_t)(b * 2048 + q0 + rowb) * 512;
#pragma unroll
    for (int dj = 0; dj < 32; dj++)
#pragma unroll
      for (int r = 0; r < 4; r++)
        orow[(size_t)r * 512 + dj * 16 + lr] =
            o[dj][r] * s0[r] + oX[(rowb + r) * 512 + dj * 16 + lr] * s1[r];
  }
}

extern "C" void kernel_launch(void* const* d_in, const int* in_sizes, int n_in,
                              void* d_out, int out_size, void* d_ws, size_t ws_size,
                              hipStream_t stream) {
  (void)in_sizes; (void)n_in; (void)out_size; (void)ws_size;
  const float* x = (const float*)d_in[0];
  const float* Wq = (const float*)d_in[1];
  const float* bq = (const float*)d_in[2];
  const float* Wk = (const float*)d_in[3];
  const float* bk = (const float*)d_in[4];
  const float* Wv = (const float*)d_in[5];
  const float* bv = (const float*)d_in[6];
  float* out = (float*)d_out;
  char* ws = (char*)d_ws;
  __bf16* xb = (__bf16*)(ws);
  __bf16* Qb = (__bf16*)(ws + 16777216);
  __bf16* Kb = (__bf16*)(ws + 33554432);
  __bf16* Vt = (__bf16*)(ws + 50331648);
  __bf16* Wt = (__bf16*)(ws + 67108864);

  hipFuncSetAttribute((const void*)k_fa, hipFuncAttributeMaxDynamicSharedMemorySize, 141824);

  k_xconv<<<4096, 256, 0, stream>>>(x, xb);
  k_wt<<<dim3(16, 16, 3), 256, 0, stream>>>(Wq, Wk, Wv, Wt);
  k_gemm<<<dim3(512, 3), 256, 0, stream>>>(xb, Wt, bq, bk, bv, Qb, Kb, Vt);
  k_fa<<<256, 512, 141824, stream>>>(Qb, Kb, Vt, out);
}

// Round 4
// 223.235 us; speedup vs baseline: 1.4140x; 1.4113x over previous
//
#include <hip/hip_runtime.h>

// B=8, N=2048, D_IN=D_OUT=512. out fp32 [8,2048,512].
// ws layout (bytes): xb@0 (16M), Qb@16M, Kb@32M, Vt@48M, Wt@64M(+1.5M).

typedef __bf16 bf16x8 __attribute__((ext_vector_type(8)));
typedef float f32x4 __attribute__((ext_vector_type(4)));

#define AS1G __attribute__((address_space(1)))
#define AS3L __attribute__((address_space(3)))

__device__ __forceinline__ void gload16(const void* g, void* l) {
  __builtin_amdgcn_global_load_lds((const AS1G void*)g, (AS3L void*)l, 16, 0, 0);
}

// ---------------- x fp32 -> bf16 ----------------
__global__ __launch_bounds__(256) void k_xconv(const float* __restrict__ x, __bf16* __restrict__ xb) {
  size_t i = ((size_t)blockIdx.x * 256 + threadIdx.x) * 8;
  const float4* p = (const float4*)(x + i);
  float4 a = p[0], b = p[1];
  bf16x8 v;
  v[0] = (__bf16)a.x; v[1] = (__bf16)a.y; v[2] = (__bf16)a.z; v[3] = (__bf16)a.w;
  v[4] = (__bf16)b.x; v[5] = (__bf16)b.y; v[6] = (__bf16)b.z; v[7] = (__bf16)b.w;
  *(bf16x8*)(xb + i) = v;
}

// ---------------- W [d][e] fp32 -> Wt [z][e][d] bf16 ----------------
__global__ __launch_bounds__(256) void k_wt(const float* __restrict__ Wq, const float* __restrict__ Wk,
                                            const float* __restrict__ Wv, __bf16* __restrict__ Wt) {
  __shared__ float t[32][33];
  int z = blockIdx.z;
  const float* W = (z == 0) ? Wq : (z == 1 ? Wk : Wv);
  int r0 = blockIdx.y * 32, c0 = blockIdx.x * 32;
  int tr = threadIdx.x >> 5, tc = threadIdx.x & 31;
#pragma unroll
  for (int p = 0; p < 4; p++)
    t[tr + p * 8][tc] = W[(size_t)(r0 + tr + p * 8) * 512 + c0 + tc];
  __syncthreads();
#pragma unroll
  for (int p = 0; p < 4; p++)
    Wt[(size_t)z * 262144 + (size_t)(c0 + tr + p * 8) * 512 + r0 + tc] = (__bf16)t[tc][tr + p * 8];
}

// ---------------- fused QKV GEMM: C = xb * Wz^T + bias ----------------
// 128x128 tile, BK=64, 4 waves (2x2 of 64x64), 16x16x32 bf16 MFMA.
// z==0 -> Qb (pre-scaled for exp2 softmax), z==1 -> Kb, z==2 -> Vt (TRANSPOSED store).
__global__ __launch_bounds__(256) void k_gemm(const __bf16* __restrict__ xb, const __bf16* __restrict__ Wt,
                                              const float* __restrict__ bq, const float* __restrict__ bk,
                                              const float* __restrict__ bv,
                                              __bf16* __restrict__ Qb, __bf16* __restrict__ Kb,
                                              __bf16* __restrict__ Vt) {
  __shared__ __bf16 sA[128 * 64];
  __shared__ __bf16 sB[128 * 64];
  int z = blockIdx.y;
  int bx = blockIdx.x;
  int m0 = (bx >> 2) * 128, e0 = (bx & 3) * 128;
  int tid = threadIdx.x, w = tid >> 6, l = tid & 63;
  int lr = l & 15, lg = l >> 4;
  int wm = (w & 1) * 64, wn = (w >> 1) * 64;
  const float* bias = (z == 0) ? bq : (z == 1 ? bk : bv);
  const __bf16* Wz = Wt + (size_t)z * 262144;

  float bval[4];
#pragma unroll
  for (int fn = 0; fn < 4; fn++) bval[fn] = bias[e0 + wn + fn * 16 + lr];

  f32x4 zero4 = {0.f, 0.f, 0.f, 0.f};
  f32x4 acc[4][4];
#pragma unroll
  for (int fm = 0; fm < 4; fm++)
#pragma unroll
    for (int fn = 0; fn < 4; fn++) acc[fm][fn] = zero4;

#pragma unroll 1
  for (int kt = 0; kt < 8; kt++) {
#pragma unroll
    for (int ii = 0; ii < 4; ii++) {
      int rt = (w * 4 + ii) * 8 + (l >> 3);
      int sw = ((l & 7) ^ (l >> 3)) << 3;
      gload16(xb + (size_t)(m0 + rt) * 512 + kt * 64 + sw, sA + (w * 4 + ii) * 512);
      gload16(Wz + (size_t)(e0 + rt) * 512 + kt * 64 + sw, sB + (w * 4 + ii) * 512);
    }
    __syncthreads();
#pragma unroll
    for (int kc = 0; kc < 2; kc++) {
      bf16x8 af[4], bfr[4];
#pragma unroll
      for (int f = 0; f < 4; f++) {
        int ra = wm + f * 16 + lr;
        af[f] = *(const bf16x8*)(sA + ra * 64 + (((kc * 4 + lg) ^ (ra & 7)) << 3));
        int rb = wn + f * 16 + lr;
        bfr[f] = *(const bf16x8*)(sB + rb * 64 + (((kc * 4 + lg) ^ (rb & 7)) << 3));
      }
#pragma unroll
      for (int fm = 0; fm < 4; fm++)
#pragma unroll
        for (int fn = 0; fn < 4; fn++)
          acc[fm][fn] = __builtin_amdgcn_mfma_f32_16x16x32_bf16(af[fm], bfr[fn], acc[fm][fn], 0, 0, 0);
    }
    __syncthreads();
  }

  if (z == 2) {
    // V transposed: Vt[b][e][n], b = row>>11, n = row&2047. 4 consecutive n per lane -> 8B store.
    int bb = m0 >> 11;
#pragma unroll
    for (int fm = 0; fm < 4; fm++) {
      int nl = (m0 & 2047) + wm + fm * 16 + lg * 4;
#pragma unroll
      for (int fn = 0; fn < 4; fn++) {
        alignas(8) __bf16 tmp[4];
#pragma unroll
        for (int r = 0; r < 4; r++) tmp[r] = (__bf16)(acc[fm][fn][r] + bval[fn]);
        *(float2*)(Vt + (size_t)bb * 1048576 + (size_t)(e0 + wn + fn * 16 + lr) * 2048 + nl) =
            *(float2*)tmp;
      }
    }
  } else {
    __bf16* dst = (z == 0) ? Qb : Kb;
    const float qmul = (z == 0) ? (1.4426950408889634f * 0.044194173824159216f) : 1.0f;
#pragma unroll
    for (int fm = 0; fm < 4; fm++)
#pragma unroll
      for (int fn = 0; fn < 4; fn++)
#pragma unroll
        for (int r = 0; r < 4; r++) {
          float v = (acc[fm][fn][r] + bval[fn]) * qmul;
          dst[(size_t)(m0 + wm + fm * 16 + lg * 4 + r) * 512 + e0 + wn + fn * 16 + lr] = (__bf16)v;
        }
  }
}

// ---------------- flash attention, D-split block pairs ----------------
// grid 512: b = blk&7 (XCD pin), qt = (blk>>3)&31, dh = blk>>8 (output D-half).
// 256 threads = 4 waves, each wave owns 16 q-rows (64 rows/block). KVBLK=32.
// Each block: full QK^T (512 dims, duplicated across the dh pair) + softmax,
// PV + output only for its 256 d-columns -> o[] = 64 VGPRs, no merge needed.
// LDS 53KB static -> with ~200 VGPR gives 2 blocks/CU (independent barrier
// domains: one block's vmcnt/barrier drain overlaps the other's MFMA).
// NOTE: 512-thread blocks pin VGPR budget to 128 (rounds 2-3: spills, +21MB
// scratch writes). 256-thread blocks allocate properly (232 VGPR, round 1).
__global__ __launch_bounds__(256, 2) void k_fa(const __bf16* __restrict__ Qb, const __bf16* __restrict__ Kb,
                                               const __bf16* __restrict__ Vt, float* __restrict__ out) {
  __shared__ __bf16 sK[32 * 512];   // [32 kv][512 d], XOR-8 chunk swizzle
  __shared__ __bf16 sV[128 * 64];   // paired d-rows: row rr = d>>1, 64 = 2x(32 kv), XOR swizzle
  __shared__ __bf16 sPall[4 * 640]; // per-wave [16][40]

  int tid = threadIdx.x;
  int w = tid >> 6, l = tid & 63;
  int lr = l & 15, lg = l >> 4;
  __bf16* sP = sPall + w * 640;

  int blk = blockIdx.x;
  int b = blk & 7;
  int q0 = ((blk >> 3) & 31) * 64;
  int d0 = (blk >> 8) * 256;

  const __bf16* Kbase = Kb + (size_t)b * 2048 * 512;
  const __bf16* Vbase = Vt + (size_t)b * 512 * 2048 + (size_t)d0 * 2048;

  // Q A-fragments in registers, full 512 dims (already scaled by log2e/sqrt(512)).
  bf16x8 qf[16];
  const __bf16* qrow = Qb + (size_t)(b * 2048 + q0 + w * 16 + lr) * 512;
#pragma unroll
  for (int dk = 0; dk < 16; dk++) qf[dk] = *(const bf16x8*)(qrow + dk * 32 + lg * 8);

  f32x4 zero4 = {0.f, 0.f, 0.f, 0.f};
  f32x4 o[16];
#pragma unroll
  for (int dj = 0; dj < 16; dj++) o[dj] = zero4;
  float m_run[4] = {-1e30f, -1e30f, -1e30f, -1e30f};
  float l_run[4] = {0.f, 0.f, 0.f, 0.f};

  // prologue: stage K(0) — 8 rows per wave, 1KB row per instr
#pragma unroll
  for (int i = 0; i < 8; i++) {
    int row = w * 8 + i;
    gload16(Kbase + (size_t)row * 512 + ((l ^ i) << 3), sK + row * 512);
  }

#pragma unroll 1
  for (int it = 0; it < 64; it++) {
    int kv0 = it * 32;
    __syncthreads();  // B1: K(it) landed; PV(it-1) sV reads done

    // stage V(it) [256 d x 32 kv as 128 paired rows] — overlaps QK
#pragma unroll
    for (int i = 0; i < 4; i++) {
      int rr = (w * 4 + i) * 8 + (l >> 3);
      int cl = (l & 7) ^ (l >> 3);
      gload16(Vbase + (size_t)(2 * rr + (cl >> 2)) * 2048 + kv0 + ((cl & 3) << 3),
              sV + (w * 4 + i) * 512);
    }

    // S = Q K^T (exp2 domain, scale folded into Q)
    f32x4 s[2] = {zero4, zero4};
#pragma unroll
    for (int dk = 0; dk < 16; dk++) {
#pragma unroll
      for (int j = 0; j < 2; j++) {
        int row = j * 16 + lr;
        bf16x8 kf = *(const bf16x8*)(sK + row * 512 + (((dk * 4 + lg) ^ (row & 7)) << 3));
        s[j] = __builtin_amdgcn_mfma_f32_16x16x32_bf16(qf[dk], kf, s[j], 0, 0, 0);
      }
    }
    __syncthreads();  // B2: V(it) landed; all sK(it) reads done

    // stage K(it+1) — overlaps softmax+PV
    if (it < 63) {
#pragma unroll
      for (int i = 0; i < 8; i++) {
        int row = w * 8 + i;
        gload16(Kbase + (size_t)(kv0 + 32 + row) * 512 + ((l ^ i) << 3), sK + row * 512);
      }
    }

    // online softmax with defer-rescale (THR=10 in log2 domain)
    float mtv[4];
#pragma unroll
    for (int r = 0; r < 4; r++) {
      float mt = fmaxf(s[0][r], s[1][r]);
#pragma unroll
      for (int msk = 1; msk <= 8; msk <<= 1) mt = fmaxf(mt, __shfl_xor(mt, msk));
      mtv[r] = mt;
    }
    float g4 = fmaxf(fmaxf(mtv[0] - m_run[0], mtv[1] - m_run[1]),
                     fmaxf(mtv[2] - m_run[2], mtv[3] - m_run[3]));
    if (__any(g4 > 10.0f)) {
#pragma unroll
      for (int r = 0; r < 4; r++) {
        float mnew = fmaxf(m_run[r], mtv[r]);
        float al = exp2f(m_run[r] - mnew);
        l_run[r] *= al;
        m_run[r] = mnew;
#pragma unroll
        for (int dj = 0; dj < 16; dj++) o[dj][r] *= al;
      }
    }
#pragma unroll
    for (int r = 0; r < 4; r++) {
      float p0 = exp2f(s[0][r] - m_run[r]);
      float p1 = exp2f(s[1][r] - m_run[r]);
      l_run[r] += p0 + p1;  // per-lane partial over lr columns
      sP[(lg * 4 + r) * 40 + lr] = (__bf16)p0;
      sP[(lg * 4 + r) * 40 + 16 + lr] = (__bf16)p1;
    }
    bf16x8 pa = *(const bf16x8*)(sP + lr * 40 + lg * 8);

    // O += P * V  (V from paired-row swizzled sV; d-range [d0, d0+256))
#pragma unroll
    for (int dj = 0; dj < 16; dj++) {
      int d = dj * 16 + lr;
      int rr = d >> 1;
      int cp = (((d & 1) << 2) | lg) ^ (rr & 7);
      bf16x8 vf = *(const bf16x8*)(sV + rr * 64 + (cp << 3));
      o[dj] = __builtin_amdgcn_mfma_f32_16x16x32_bf16(pa, vf, o[dj], 0, 0, 0);
    }
  }

  // reduce per-lane l partials across the 16 lr lanes
#pragma unroll
  for (int r = 0; r < 4; r++) {
#pragma unroll
    for (int msk = 1; msk <= 8; msk <<= 1) l_run[r] += __shfl_xor(l_run[r], msk);
  }
  float inv[4];
#pragma unroll
  for (int r = 0; r < 4; r++) inv[r] = 1.0f / l_run[r];

  float* orow = out + (size_t)(b * 2048 + q0 + w * 16 + lg * 4) * 512 + d0;
#pragma unroll
  for (int dj = 0; dj < 16; dj++)
#pragma unroll
    for (int r = 0; r < 4; r++)
      orow[(size_t)r * 512 + dj * 16 + lr] = o[dj][r] * inv[r];
}

extern "C" void kernel_launch(void* const* d_in, const int* in_sizes, int n_in,
                              void* d_out, int out_size, void* d_ws, size_t ws_size,
                              hipStream_t stream) {
  (void)in_sizes; (void)n_in; (void)out_size; (void)ws_size;
  const float* x = (const float*)d_in[0];
  const float* Wq = (const float*)d_in[1];
  const float* bq = (const float*)d_in[2];
  const float* Wk = (const float*)d_in[3];
  const float* bk = (const float*)d_in[4];
  const float* Wv = (const float*)d_in[5];
  const float* bv = (const float*)d_in[6];
  float* out = (float*)d_out;
  char* ws = (char*)d_ws;
  __bf16* xb = (__bf16*)(ws);
  __bf16* Qb = (__bf16*)(ws + 16777216);
  __bf16* Kb = (__bf16*)(ws + 33554432);
  __bf16* Vt = (__bf16*)(ws + 50331648);
  __bf16* Wt = (__bf16*)(ws + 67108864);

  k_xconv<<<4096, 256, 0, stream>>>(x, xb);
  k_wt<<<dim3(16, 16, 3), 256, 0, stream>>>(Wq, Wk, Wv, Wt);
  k_gemm<<<dim3(512, 3), 256, 0, stream>>>(xb, Wt, bq, bk, bv, Qb, Kb, Vt);
  k_fa<<<512, 256, 0, stream>>>(Qb, Kb, Vt, out);
}